// Round 10
// baseline (1406.855 us; speedup 1.0000x reference)
//
#include <hip/hip_runtime.h>
#include <cstdint>
#include <cstddef>

using f32x4 = __attribute__((ext_vector_type(4))) float;
using short8 = __attribute__((ext_vector_type(8))) short;

// ---------------- bf16 helpers ----------------
__device__ __forceinline__ float blo(unsigned int u) { return __uint_as_float(u << 16); }
__device__ __forceinline__ float bhi(unsigned int u) { return __uint_as_float(u & 0xffff0000u); }
__device__ __forceinline__ unsigned short f2b(float f) {
  unsigned int i = __float_as_uint(f);
  return (unsigned short)((i + 0x7fffu + ((i >> 16) & 1u)) >> 16);  // RTNE
}
__device__ __forceinline__ unsigned int packb2(float a, float b) {
  return (unsigned int)f2b(a) | ((unsigned int)f2b(b) << 16);
}
// async global->LDS, 16B per lane (HW dest = wave-uniform base + lane*16; lane0's ptr is base)
__device__ __forceinline__ void gload_lds16(const void* g, void* l) {
  typedef __attribute__((address_space(1))) const unsigned int gui_t;
  typedef __attribute__((address_space(3))) unsigned int lui_t;
  __builtin_amdgcn_global_load_lds((gui_t*)(uintptr_t)g, (lui_t*)(uintptr_t)l, 16, 0, 0);
}

// ---------------- diagnostic sentinel ----------------
__global__ void k_sentinel(float* out, long long total, float v) {
  long long i = (long long)blockIdx.x * blockDim.x + threadIdx.x;
  long long stride = (long long)gridDim.x * blockDim.x;
  for (; i < total; i += stride) out[i] = v;
}

// ---------------- graph prep ----------------
__global__ void k_init_deg(int* deg, int n) {
  int i = blockIdx.x * blockDim.x + threadIdx.x;
  if (i < n) deg[i] = 1;
}
__global__ void k_count(const int* __restrict__ ei, int* __restrict__ deg, int e) {
  int i = blockIdx.x * blockDim.x + threadIdx.x;
  if (i < e) atomicAdd(&deg[ei[e + i]], 1);
}
__global__ void k_dinv(const int* __restrict__ deg, float* __restrict__ dinv, int n) {
  int i = blockIdx.x * blockDim.x + threadIdx.x;
  if (i < n) dinv[i] = rsqrtf((float)deg[i]);
}
__global__ void k_scan(const int* __restrict__ deg, int* __restrict__ offs, int n) {
  __shared__ int sums[1024];
  int tid = threadIdx.x;
  int chunk = (n + 1023) / 1024;
  int s0 = tid * chunk, s1 = s0 + chunk;
  if (s1 > n) s1 = n;
  if (s0 > n) s0 = n;
  int s = 0;
  for (int i = s0; i < s1; i++) s += deg[i];
  sums[tid] = s;
  __syncthreads();
  if (tid == 0) {
    int acc = 0;
    for (int i = 0; i < 1024; i++) { int v = sums[i]; sums[i] = acc; acc += v; }
  }
  __syncthreads();
  int off = sums[tid];
  for (int i = s0; i < s1; i++) { offs[i] = off; off += deg[i]; }
  if (tid == 1023) offs[n] = off;
}
__global__ void k_copy_int(int* __restrict__ dst, const int* __restrict__ src, int n) {
  int i = blockIdx.x * blockDim.x + threadIdx.x;
  if (i < n) dst[i] = src[i];
}
__global__ void k_copy_u4(uint4* __restrict__ dst, const uint4* __restrict__ src, int n16) {
  int i = blockIdx.x * blockDim.x + threadIdx.x;
  int stride = gridDim.x * blockDim.x;
  for (; i < n16; i += stride) dst[i] = src[i];
}
__global__ void k_fill_edges(const int* __restrict__ ei, int e, int* __restrict__ cursor,
                             unsigned short* __restrict__ colv) {
  int i = blockIdx.x * blockDim.x + threadIdx.x;
  if (i < e) {
    int s = ei[i], d = ei[e + i];
    int pos = atomicAdd(&cursor[d], 1);
    colv[pos] = (unsigned short)s;
  }
}
__global__ void k_fill_loops(int* __restrict__ cursor, unsigned short* __restrict__ colv, int n) {
  int i = blockIdx.x * blockDim.x + threadIdx.x;
  if (i < n) {
    int pos = atomicAdd(&cursor[i], 1);
    colv[pos] = (unsigned short)i;
  }
}
// merged meta relocation (offs, colv, dinv -> ws copies) in one launch
__global__ void k_copy_meta(const int* __restrict__ offs, int* __restrict__ offs_c,
                            const int* __restrict__ colv, int* __restrict__ colv_c, int colv_ints,
                            const float* __restrict__ dinv, float* __restrict__ dinv_c, int n) {
  int i = blockIdx.x * blockDim.x + threadIdx.x;
  int stride = gridDim.x * blockDim.x;
  for (int k = i; k <= n; k += stride) offs_c[k] = offs[k];
  for (int k = i; k < colv_ints; k += stride) colv_c[k] = colv[k];
  for (int k = i; k < n; k += stride) dinv_c[k] = dinv[k];
}

// ---------------- conversions ----------------
__global__ void k_cvt_bf16(const float2* __restrict__ in, unsigned int* __restrict__ out, long long total) {
  long long i = (long long)blockIdx.x * blockDim.x + threadIdx.x;
  long long stride = (long long)gridDim.x * blockDim.x;
  for (; i < total; i += stride) {
    float2 v = in[i];
    out[i] = packb2(v.x, v.y);
  }
}
// in: [K][M] fp32 row-major -> out: [Mout][K] bf16 (rows >= M zero-filled)
__global__ void k_transpose_cvt(const float* __restrict__ in, unsigned short* __restrict__ out,
                                int K, int M, int Mout) {
  __shared__ float tile[32][33];
  int kb = blockIdx.x * 32;
  int mb = blockIdx.y * 32;
  int tx = threadIdx.x, ty = threadIdx.y;  // 32 x 8
#pragma unroll
  for (int j = 0; j < 4; j++) {
    int k = kb + ty + j * 8, m = mb + tx;
    tile[ty + j * 8][tx] = (k < K && m < M) ? in[(size_t)k * M + m] : 0.0f;
  }
  __syncthreads();
#pragma unroll
  for (int j = 0; j < 4; j++) {
    int m = mb + ty + j * 8, k = kb + tx;
    if (m < Mout && k < K) out[(size_t)m * K + k] = f2b(tile[tx][ty + j * 8]);
  }
}

// ---------------- layer-1 aggregation: bf16 gather (D=512) ----------------
__global__ void k_aggregate_512(const unsigned int* __restrict__ in, unsigned short* __restrict__ out,
                                const int* __restrict__ offs, const unsigned short* __restrict__ colv,
                                const float* __restrict__ dinv) {
  int i = blockIdx.x;
  int tid = threadIdx.x;  // 256 threads, 1 uint (2 bf16) each
  float di = dinv[i];
  int p0 = offs[i], p1 = offs[i + 1];
  float a0 = 0.f, a1 = 0.f;
  for (int p = p0; p < p1; p++) {
    int c = (int)colv[p];
    float wgt = dinv[c] * di;
    unsigned int u = in[(size_t)c * 256 + tid];
    a0 += wgt * blo(u); a1 += wgt * bhi(u);
  }
  ((unsigned int*)out)[(size_t)i * 256 + tid] = packb2(a0, a1);
}

// ---------------- layer-2 aggregation fused with pairnorm-apply + relu ----------------
__global__ void k_aggregate_pn(const unsigned short* __restrict__ in, unsigned short* __restrict__ outws,
                               unsigned short* __restrict__ outtail, int rsplit,
                               const int* __restrict__ offs, const unsigned short* __restrict__ colv,
                               const float* __restrict__ dinv, const float* __restrict__ meanv,
                               const float* __restrict__ scalev) {
  int i = blockIdx.x;
  int tid = threadIdx.x;
  float di = dinv[i];
  float s = scalev[0];
  float m[8];
#pragma unroll
  for (int j = 0; j < 8; j++) m[j] = meanv[tid * 8 + j];
  int p0 = offs[i], p1 = offs[i + 1];
  const uint4* inv = (const uint4*)in;
  float a[8] = {};
  for (int p = p0; p < p1; p++) {
    int c = (int)colv[p];
    float wgt = dinv[c] * di;
    uint4 u = inv[(size_t)c * 256 + tid];
    a[0] += wgt * fmaxf((blo(u.x) - m[0]) * s, 0.f);
    a[1] += wgt * fmaxf((bhi(u.x) - m[1]) * s, 0.f);
    a[2] += wgt * fmaxf((blo(u.y) - m[2]) * s, 0.f);
    a[3] += wgt * fmaxf((bhi(u.y) - m[3]) * s, 0.f);
    a[4] += wgt * fmaxf((blo(u.z) - m[4]) * s, 0.f);
    a[5] += wgt * fmaxf((bhi(u.z) - m[5]) * s, 0.f);
    a[6] += wgt * fmaxf((blo(u.w) - m[6]) * s, 0.f);
    a[7] += wgt * fmaxf((bhi(u.w) - m[7]) * s, 0.f);
  }
  uint4 o;
  o.x = packb2(a[0], a[1]); o.y = packb2(a[2], a[3]);
  o.z = packb2(a[4], a[5]); o.w = packb2(a[6], a[7]);
  char* base = (i < rsplit) ? (char*)outws + (size_t)i * 4096
                            : (char*)outtail + (size_t)(i - rsplit) * 4096;
  ((uint4*)base)[tid] = o;
}

// ================= 256x256 8-phase GEMM, deep prefetch; XCD-column B-residency ==============
// Grid must be (8, MT). Remap: bx = flat&7 (n-tile == XCD, B panel 1 MB stays L2-resident),
// by = flat>>3. Kills the 187x B re-read from L3 (1.57 GB -> ~8 MB).
template <int MQ>
__device__ __forceinline__ void load_a(const char* ldsA, short8 (&a)[4][2], int wm, int lane) {
  const int frow = lane & 15;
  const int cb0 = (lane >> 4) << 4;
  const int xorb = (lane & 7) << 4;
#pragma unroll
  for (int i = 0; i < 4; i++)
#pragma unroll
    for (int kk = 0; kk < 2; kk++)
      a[i][kk] = *(const short8*)(ldsA + (wm * 128 + MQ * 64 + i * 16 + frow) * 128 +
                                  ((kk * 64 + cb0) ^ xorb));
}
template <int NQ>
__device__ __forceinline__ void load_b(const char* ldsB, short8 (&b)[2][2][2], int wn, int lane) {
  const int frow = lane & 15;
  const int cb0 = (lane >> 4) << 4;
  const int xorb = (lane & 7) << 4;
#pragma unroll
  for (int j = 0; j < 2; j++)
#pragma unroll
    for (int kk = 0; kk < 2; kk++)
      b[NQ][j][kk] = *(const short8*)(ldsB + (wn * 64 + NQ * 32 + j * 16 + frow) * 128 +
                                      ((kk * 64 + cb0) ^ xorb));
}
template <int MQ, int NQ>
__device__ __forceinline__ void mfma_q(short8 (&a)[4][2], short8 (&b)[2][2][2], f32x4 (&acc)[8][4]) {
  __builtin_amdgcn_s_setprio(1);
#pragma unroll
  for (int i = 0; i < 4; i++)
#pragma unroll
    for (int j = 0; j < 2; j++)
#pragma unroll
      for (int kk = 0; kk < 2; kk++)
        acc[MQ * 4 + i][NQ * 2 + j] =
            __builtin_amdgcn_mfma_f32_16x16x32_bf16(a[i][kk], b[NQ][j][kk], acc[MQ * 4 + i][NQ * 2 + j], 0, 0, 0);
  __builtin_amdgcn_s_setprio(0);
}

__global__ __launch_bounds__(512, 2) void k_gemm256(const unsigned short* __restrict__ A,
                                                    const char* __restrict__ a_tail, int rsplit,
                                                    const unsigned short* __restrict__ BT,
                                                    const float* __restrict__ bias,
                                                    float* __restrict__ colsum, float* __restrict__ ssq,
                                                    unsigned short* __restrict__ Cout,
                                                    int M, int K, int Nout, int m_base) {
  __shared__ __align__(16) char smem[131072];  // [Abuf0 32K][Bbuf0 32K][Abuf1 32K][Bbuf1 32K]
  const int t = threadIdx.x;
  const int lane = t & 63;
  const int wid = t >> 6;
  const int wm = wid >> 2, wn = wid & 3;
  // XCD-column affinity: HW assigns workgroups round-robin by flat id (xcd = flat & 7).
  // bx = flat&7 pins each n-tile column to one XCD -> its 1 MB B panel stays L2-resident.
  int flat = blockIdx.y * gridDim.x + blockIdx.x;
  int bx = flat & 7;
  int by = flat >> 3;
  const int n0 = bx * 256;
  const int m0 = m_base + by * 256;
  const size_t rowK = (size_t)K * 2;
  const int NT = K >> 6;

  const int rA = t >> 3;
  const int colS = (((t & 7) ^ ((t >> 3) & 7)) << 4);  // pre-swizzled source column (rule 21)

  auto rowptrA = [&](int r) -> const char* {
    int gr = m0 + r; if (gr >= M) gr = M - 1;
    return (gr < rsplit ? (const char*)A + (size_t)gr * rowK
                        : a_tail + (size_t)(gr - rsplit) * rowK) + colS;
  };
  const char* sA00 = rowptrA(rA);          // mq0,l0: LDS rows [0,64)
  const char* sA01 = rowptrA(128 + rA);    // mq0,l1: LDS rows [128,192)
  const char* sA10 = rowptrA(64 + rA);     // mq1,l0: LDS rows [64,128)
  const char* sA11 = rowptrA(192 + rA);    // mq1,l1: LDS rows [192,256)
  const int rbl = (t >> 8) * 64 + ((t >> 3) & 31);  // B row core
  const int rB00 = rbl, rB01 = 128 + rbl;           // nq0 l0/l1
  const int rB10 = 32 + rbl, rB11 = 160 + rbl;      // nq1 l0/l1
  const char* sB00 = (const char*)BT + (size_t)(n0 + rB00) * rowK + colS;
  const char* sB01 = (const char*)BT + (size_t)(n0 + rB01) * rowK + colS;
  const char* sB10 = (const char*)BT + (size_t)(n0 + rB10) * rowK + colS;
  const char* sB11 = (const char*)BT + (size_t)(n0 + rB11) * rowK + colS;
  const int t16 = t * 16;
  const int dA00 = t16, dA01 = 16384 + t16, dA10 = 8192 + t16, dA11 = 24576 + t16;
  const int c7 = (t & 7) * 16;
  const int dB00 = 32768 + rB00 * 128 + c7, dB01 = 32768 + rB01 * 128 + c7;
  const int dB10 = 32768 + rB10 * 128 + c7, dB11 = 32768 + rB11 * 128 + c7;

  f32x4 acc[8][4] = {};
  short8 a[4][2], b[2][2][2];

  // ---- prologue: tile0 -> buf0 (8 loads); A(t1) -> buf1 (4 loads); retire tile0 only ----
  gload_lds16(sA00, smem + dA00); gload_lds16(sA01, smem + dA01);
  gload_lds16(sA10, smem + dA10); gload_lds16(sA11, smem + dA11);
  gload_lds16(sB00, smem + dB00); gload_lds16(sB01, smem + dB01);
  gload_lds16(sB10, smem + dB10); gload_lds16(sB11, smem + dB11);
  gload_lds16(sA00 + 128, smem + 65536 + dA00); gload_lds16(sA01 + 128, smem + 65536 + dA01);
  gload_lds16(sA10 + 128, smem + 65536 + dA10); gload_lds16(sA11 + 128, smem + 65536 + dA11);
  sA00 += 256; sA01 += 256; sA10 += 256; sA11 += 256;  // A pointers now at tile kt+2 (kt=0)
  sB00 += 128; sB01 += 128; sB10 += 128; sB11 += 128;  // B pointers now at tile kt+1
  asm volatile("s_waitcnt vmcnt(4)" ::: "memory");     // tile0's 8 retired; A(t1) in flight
  asm volatile("s_barrier" ::: "memory");
  load_a<0>((const char*)smem, a, wm, lane);
  load_b<0>((const char*)smem + 32768, b, wn, lane);

  for (int kt = 0; kt < NT; ++kt) {
    const int cbo = (kt & 1) << 16;
    const int sbo = cbo ^ 65536;
    const char* LA = (const char*)smem + cbo;
    const char* LB = LA + 32768;
    const char* NA = (const char*)smem + sbo;
    const char* NB = NA + 32768;
    char* SB = smem + sbo;   // B dest: tile kt+1
    char* SA = smem + cbo;   // A dest: tile kt+2 (current A region consumed by ph1-end)
    // ---- ph0 (mq0,nq0): stage B0(kt+1) | vmcnt(6) | MFMA | preload b1<-B1(kt) ----
    gload_lds16(sB00, SB + dB00); gload_lds16(sB01, SB + dB01);
    asm volatile("s_waitcnt vmcnt(6)" ::: "memory");
    asm volatile("s_barrier" ::: "memory");
    mfma_q<0, 0>(a, b, acc);
    load_b<1>(LB, b, wn, lane);
    __builtin_amdgcn_sched_barrier(0);
    asm volatile("s_barrier" ::: "memory");
    // ---- ph1 (mq0,nq1): stage B1(kt+1) | MFMA | preload a<-A1(kt) ----
    gload_lds16(sB10, SB + dB10); gload_lds16(sB11, SB + dB11);
    asm volatile("s_barrier" ::: "memory");
    mfma_q<0, 1>(a, b, acc);
    load_a<1>(LA, a, wm, lane);
    __builtin_amdgcn_sched_barrier(0);
    asm volatile("s_barrier" ::: "memory");
    // ---- ph2 (mq1,nq0): stage A0(kt+2) into CURRENT buffer | MFMA ----
    gload_lds16(sA00, SA + dA00); gload_lds16(sA01, SA + dA01);
    asm volatile("s_barrier" ::: "memory");
    mfma_q<1, 0>(a, b, acc);
    __builtin_amdgcn_sched_barrier(0);
    asm volatile("s_barrier" ::: "memory");
    // ---- ph3 (mq1,nq1): stage A1(kt+2) | vmcnt(6) | MFMA | preload a,b0 of tile kt+1 ----
    gload_lds16(sA10, SA + dA10); gload_lds16(sA11, SA + dA11);
    asm volatile("s_waitcnt vmcnt(6)" ::: "memory");
    asm volatile("s_barrier" ::: "memory");
    mfma_q<1, 1>(a, b, acc);
    load_a<0>(NA, a, wm, lane);
    load_b<0>(NB, b, wn, lane);
    __builtin_amdgcn_sched_barrier(0);
    asm volatile("s_barrier" ::: "memory");
    sA00 += 128; sA01 += 128; sA10 += 128; sA11 += 128;
    sB00 += 128; sB01 += 128; sB10 += 128; sB11 += 128;
  }
  // tail lookahead reads at most 256B past each row's K extent -> lands in adjacent
  // allocated regions, data never consumed as valid.

  // ---- epilogue: bias + bf16 store + fused column stats ----
  const int rrow = (lane >> 4) * 4;
  const int ccol = lane & 15;
  float ss = 0.f;
  float csum[4] = {0.f, 0.f, 0.f, 0.f};
#pragma unroll
  for (int f = 0; f < 8; f++) {
#pragma unroll
    for (int g = 0; g < 4; g++) {
      int col = n0 + wn * 64 + g * 16 + ccol;
      float bv = bias[col];
#pragma unroll
      for (int r = 0; r < 4; r++) {
        int row = m0 + wm * 128 + f * 16 + rrow + r;
        if (row < M) {
          float v = acc[f][g][r] + bv;
          Cout[(size_t)row * Nout + col] = f2b(v);
          csum[g] += v; ss += v * v;
        }
      }
    }
  }
#pragma unroll
  for (int g = 0; g < 4; g++) {
    float w = csum[g];
    w += __shfl_xor(w, 16);
    w += __shfl_xor(w, 32);
    if (lane < 16) atomicAdd(&colsum[n0 + wn * 64 + g * 16 + lane], w);
  }
  for (int mk = 32; mk >= 1; mk >>= 1) ss += __shfl_xor(ss, mk);
  if (lane == 0) atomicAdd(ssq, ss);
}

// ---------------- layer-3 GEMM with fused pairnorm+relu on A ----------------
__global__ __launch_bounds__(256) void k_gemm3_pn(const unsigned short* __restrict__ A,
                                                  const float* __restrict__ meanv,
                                                  const float* __restrict__ scalev,
                                                  const unsigned short* __restrict__ BT,
                                                  float* __restrict__ Cout,
                                                  int M, int K, int Nout) {
  constexpr int BK = 64;
  constexpr int FN = 4;
  __shared__ __align__(16) unsigned short lA[64 * BK];
  __shared__ __align__(16) unsigned short lB[64 * BK];
  const int tid = threadIdx.x;
  const int lane = tid & 63;
  const int wid = tid >> 6;
  const int m0 = blockIdx.y * 64;
  const int wrow = wid * 16;
  const size_t rowK = (size_t)K * 2;
  const float s = scalev[0];

  f32x4 acc[FN] = {};
  const int frow = lane & 15;
  const int kcol8 = (lane >> 4) * 8;
  const int xorb = (lane & 7) << 4;

  for (int k0 = 0; k0 < K; k0 += BK) {
#pragma unroll
    for (int c = 0; c < 2; c++) {
      int o = c * 4096 + tid * 16;
      int r = o >> 7;
      int kb = o & 127;
      int gr = m0 + r; if (gr >= M) gr = M - 1;
      uint4 u = *(const uint4*)((const char*)A + (size_t)gr * rowK + (size_t)k0 * 2 + kb);
      int col = k0 + (kb >> 1);
      float4 m0v = *(const float4*)&meanv[col];
      float4 m1v = *(const float4*)&meanv[col + 4];
      uint4 g;
      g.x = packb2(fmaxf((blo(u.x) - m0v.x) * s, 0.f), fmaxf((bhi(u.x) - m0v.y) * s, 0.f));
      g.y = packb2(fmaxf((blo(u.y) - m0v.z) * s, 0.f), fmaxf((bhi(u.y) - m0v.w) * s, 0.f));
      g.z = packb2(fmaxf((blo(u.z) - m1v.x) * s, 0.f), fmaxf((bhi(u.z) - m1v.y) * s, 0.f));
      g.w = packb2(fmaxf((blo(u.w) - m1v.z) * s, 0.f), fmaxf((bhi(u.w) - m1v.w) * s, 0.f));
      *(uint4*)((char*)lA + (o ^ ((r & 7) << 4))) = g;
    }
#pragma unroll
    for (int c = 0; c < 2; c++) {
      int o = c * 4096 + tid * 16;
      int r = o >> 7;
      int kbs = (o & 127) ^ ((r & 7) << 4);
      gload_lds16((const char*)BT + (size_t)r * rowK + (size_t)k0 * 2 + kbs, (char*)lB + o);
    }
    __syncthreads();
#pragma unroll
    for (int kk = 0; kk < BK; kk += 32) {
      short8 af = *(const short8*)((const char*)lA + (wrow + frow) * 128 + (((kk + kcol8) * 2) ^ xorb));
#pragma unroll
      for (int u = 0; u < FN; u++) {
        short8 bf = *(const short8*)((const char*)lB + (u * 16 + frow) * 128 + (((kk + kcol8) * 2) ^ xorb));
        acc[u] = __builtin_amdgcn_mfma_f32_16x16x32_bf16(af, bf, acc[u], 0, 0, 0);
      }
    }
    __syncthreads();
  }

  const int rrow = (lane >> 4) * 4;
  const int ccol = lane & 15;
#pragma unroll
  for (int u = 0; u < FN; u++) {
#pragma unroll
    for (int r = 0; r < 4; r++) {
      int row = m0 + wrow + rrow + r;
      int col = u * 16 + ccol;
      if (row < M && col < Nout)
        Cout[(size_t)row * Nout + col] = acc[u][r];
    }
  }
}

// ---------------- pairnorm scalars ----------------
__global__ void k_zero_stats(float* colsum, float* ssq, int n) {
  int i = blockIdx.x * blockDim.x + threadIdx.x;
  if (i < n) colsum[i] = 0.f;
  if (i == 0) ssq[0] = 0.f;
}
// computes meanv/scalev, then re-zeroes colsum/ssq for the next layer's atomics
__global__ void k_finalize(float* __restrict__ colsum, float* __restrict__ ssq,
                           float* __restrict__ meanv, float* __restrict__ scalev, int nrows, int ncols) {
  __shared__ float red[1024];
  int tid = threadIdx.x;
  float m2 = 0.f;
  for (int c = tid; c < ncols; c += 1024) {
    float m = colsum[c] / (float)nrows;
    meanv[c] = m;
    m2 += m * m;
    colsum[c] = 0.f;
  }
  red[tid] = m2;
  __syncthreads();
  for (int s = 512; s > 0; s >>= 1) {
    if (tid < s) red[tid] += red[tid + s];
    __syncthreads();
  }
  if (tid == 0) {
    float sstot = ssq[0] - (float)nrows * red[0];
    scalev[0] = rsqrtf(1e-6f + sstot / (float)nrows);
    ssq[0] = 0.f;
  }
}

// ---------------- final aggregation at D=40 (fp32) + bias, 4 rows/block ----------------
__global__ void k_aggregate_out(const float* __restrict__ t, const int* __restrict__ offs,
                                const unsigned short* __restrict__ colv, const float* __restrict__ dinv,
                                const float* __restrict__ b3, float* __restrict__ outp, int n, int ncls) {
  int i = blockIdx.x * 4 + (threadIdx.x >> 6);
  int j = threadIdx.x & 63;
  if (i < n && j < ncls) {
    float di = dinv[i];
    float acc = b3[j];
    for (int p = offs[i]; p < offs[i + 1]; p++) {
      int c = (int)colv[p];
      acc += dinv[c] * di * t[(size_t)c * ncls + j];
    }
    outp[(size_t)i * ncls + j] = acc;
  }
}

extern "C" void kernel_launch(void* const* d_in, const int* in_sizes, int n_in,
                              void* d_out, int out_size, void* d_ws, size_t ws_size,
                              hipStream_t stream) {
  (void)n_in;
  const float* x = (const float*)d_in[0];
  const int* ei = (const int*)d_in[1];
  const float* W1 = (const float*)d_in[2];
  const float* b1 = (const float*)d_in[3];
  const float* W2 = (const float*)d_in[4];
  const float* b2 = (const float*)d_in[5];
  const float* W3 = (const float*)d_in[6];
  const float* b3 = (const float*)d_in[7];
  const int DI = 512, DH = 2048, NC = 40;
  const int n = in_sizes[0] / DI;  // 50000
  const int e = in_sizes[1] / 2;   // 200000

  // ---- memory plan (ws ~390MB + d_out 8MB overlay) ----
  const size_t BIG1B = (size_t)n * DH * 2;  // 204,800,000
  char* BIG1 = (char*)d_ws;
  char* BIG2 = (char*)d_ws + BIG1B;

  char* dob = (char*)d_out;
  int* deg = (int*)(dob + 0);
  float* dinv = (float*)(dob + 200064);
  int* offs = (int*)(dob + 400128);
  unsigned short* colv = (unsigned short*)(dob + 600192);
  float* colsum = (float*)(dob + 1100288);
  float* meanv = (float*)(dob + 1108480);
  float* ssq = (float*)(dob + 1116672);
  float* scalev = (float*)(dob + 1116928);
  char* aggtail = dob + 2097152;

  long long rows_ws = (long long)(ws_size - BIG1B) / (DH * 2);
  int rsplit = (rows_ws > n) ? n : (int)rows_ws;

  if (ws_size < 403800000UL || rsplit < 48560) {
    float v = (float)(double)(ws_size >> 20);
    k_sentinel<<<512, 256, 0, stream>>>((float*)d_out, (long long)out_size, v);
    return;
  }

  const int W2ROW0 = 47952;
  unsigned short* WT2 = (unsigned short*)(BIG1 + (size_t)W2ROW0 * 4096);
  const int PH2_MBASE = 47872;                          // 187 * 256
  const int PH2_TILES = (n - PH2_MBASE + 255) / 256;    // 9

  unsigned short* agg1 = (unsigned short*)BIG2;                 // n x 512 bf16
  unsigned short* xb = (unsigned short*)(BIG2 + 64000000);      // n x 512 bf16 (x in bf16)
  unsigned short* WT1 = (unsigned short*)(BIG2 + 120000000);    // 2 MiB
  unsigned short* agg2 = (unsigned short*)BIG2;                 // n x 2048 bf16 (rows < rsplit)
  unsigned short* WT2c = (unsigned short*)BIG2;                 // WT2 copy (rows 0..2047 dead after ph1)
  float* tbuf = (float*)BIG2;                                   // n x 40 f32
  unsigned short* WT3 = (unsigned short*)(BIG2 + 9000000);
  int* offs_c = (int*)(BIG2 + 10000000);
  unsigned short* colv_c = (unsigned short*)(BIG2 + 11000000);
  float* dinv_c = (float*)(BIG2 + 12000000);

  dim3 b256(256);
  dim3 b512(512);
  int gn = (n + 255) / 256, ge = (e + 255) / 256;

  // ---- graph prep ----
  k_init_deg<<<gn, b256, 0, stream>>>(deg, n);
  k_count<<<ge, b256, 0, stream>>>(ei, deg, e);
  k_dinv<<<gn, b256, 0, stream>>>(deg, dinv, n);
  k_scan<<<1, 1024, 0, stream>>>(deg, offs, n);
  k_copy_int<<<gn, b256, 0, stream>>>(deg, offs, n);
  k_fill_edges<<<ge, b256, 0, stream>>>(ei, e, deg, colv);
  k_fill_loops<<<gn, b256, 0, stream>>>(deg, colv, n);

  dim3 tb(32, 8);

  // ---- layer 1: h1 = (A @ x) @ W1 + b1 (stats fused) ----
  k_cvt_bf16<<<2048, b256, 0, stream>>>((const float2*)x, (unsigned int*)xb, (long long)n * DI / 2);
  k_aggregate_512<<<n, b256, 0, stream>>>((const unsigned int*)xb, agg1, offs, colv, dinv);
  k_transpose_cvt<<<dim3(DI / 32, DH / 32), tb, 0, stream>>>(W1, WT1, DI, DH, DH);
  k_zero_stats<<<(DH + 255) / 256, b256, 0, stream>>>(colsum, ssq, DH);
  k_gemm256<<<dim3(DH / 256, (n + 255) / 256), b512, 0, stream>>>(
      agg1, (const char*)agg1, n, WT1, b1, colsum, ssq, (unsigned short*)BIG1, n, DI, DH, 0);
  k_finalize<<<1, 1024, 0, stream>>>(colsum, ssq, meanv, scalev, n, DH);  // also re-zeroes stats

  // ---- layer 2: h2 = (A @ relu(pn(h1))) @ W2 + b2 ----
  k_aggregate_pn<<<n, b256, 0, stream>>>((const unsigned short*)BIG1, agg2, (unsigned short*)aggtail,
                                         rsplit, offs, colv, dinv, meanv, scalev);
  k_transpose_cvt<<<dim3(DH / 32, DH / 32), tb, 0, stream>>>(W2, WT2, DH, DH, DH);
  // phase 1: rows [0, 47872) — does not write the WT2 region (>= 47952)
  k_gemm256<<<dim3(DH / 256, 187), b512, 0, stream>>>(
      agg2, aggtail, rsplit, WT2, b2, colsum, ssq, (unsigned short*)BIG1, n, DH, DH, 0);
  // agg2 rows 0..2047 dead -> copy WT2 there, then finish rows [47872, n)
  k_copy_u4<<<2048, b256, 0, stream>>>((uint4*)WT2c, (const uint4*)WT2, (int)(8388608 / 16));
  k_gemm256<<<dim3(DH / 256, PH2_TILES), b512, 0, stream>>>(
      agg2, aggtail, rsplit, WT2c, b2, colsum, ssq, (unsigned short*)BIG1, n, DH, DH, PH2_MBASE);
  k_finalize<<<1, 1024, 0, stream>>>(colsum, ssq, meanv, scalev, n, DH);

  // ---- layer 3: out = A @ (relu(pn(h2)) @ W3) + b3  (pn fused into GEMM3 A-staging) ----
  k_transpose_cvt<<<dim3(DH / 32, 2), tb, 0, stream>>>(W3, WT3, DH, NC, 64);
  k_gemm3_pn<<<dim3(1, (n + 63) / 64), b256, 0, stream>>>(
      (const unsigned short*)BIG1, meanv, scalev, WT3, tbuf, n, DH, NC);
  k_copy_meta<<<256, b256, 0, stream>>>(offs, offs_c, (const int*)colv, (int*)colv_c, (e + n) / 2,
                                        dinv, dinv_c, n);
  k_aggregate_out<<<(n + 3) / 4, b256, 0, stream>>>(tbuf, offs_c, colv_c, dinv_c, b3,
                                                    (float*)d_out, n, NC);
}

// Round 11
// 1354.421 us; speedup vs baseline: 1.0387x; 1.0387x over previous
//
#include <hip/hip_runtime.h>
#include <cstdint>
#include <cstddef>

using f32x4 = __attribute__((ext_vector_type(4))) float;
using short8 = __attribute__((ext_vector_type(8))) short;

// ---------------- bf16 helpers ----------------
__device__ __forceinline__ float blo(unsigned int u) { return __uint_as_float(u << 16); }
__device__ __forceinline__ float bhi(unsigned int u) { return __uint_as_float(u & 0xffff0000u); }
__device__ __forceinline__ unsigned short f2b(float f) {
  unsigned int i = __float_as_uint(f);
  return (unsigned short)((i + 0x7fffu + ((i >> 16) & 1u)) >> 16);  // RTNE
}
__device__ __forceinline__ unsigned int packb2(float a, float b) {
  return (unsigned int)f2b(a) | ((unsigned int)f2b(b) << 16);
}
// async global->LDS, 16B per lane (HW dest = wave-uniform base + lane*16; lane0's ptr is base)
__device__ __forceinline__ void gload_lds16(const void* g, void* l) {
  typedef __attribute__((address_space(1))) const unsigned int gui_t;
  typedef __attribute__((address_space(3))) unsigned int lui_t;
  __builtin_amdgcn_global_load_lds((gui_t*)(uintptr_t)g, (lui_t*)(uintptr_t)l, 16, 0, 0);
}
// bijective XCD-aware remap (m204): contiguous chunk per XCD, n-fastest
__device__ __forceinline__ void xcd_remap(int gx, int gy, int& bx, int& by) {
  int nwg = gx * gy;
  int flat = by * gx + bx;
  int q = nwg >> 3, rmd = nwg & 7;
  int xcd = flat & 7, pos = flat >> 3;
  int base = (xcd < rmd) ? xcd * (q + 1) : rmd * (q + 1) + (xcd - rmd) * q;
  int nf = base + pos;
  bx = nf % gx;
  by = nf / gx;
}

// ---------------- diagnostic sentinel ----------------
__global__ void k_sentinel(float* out, long long total, float v) {
  long long i = (long long)blockIdx.x * blockDim.x + threadIdx.x;
  long long stride = (long long)gridDim.x * blockDim.x;
  for (; i < total; i += stride) out[i] = v;
}

// ---------------- graph prep ----------------
__global__ void k_init_deg(int* deg, int n) {
  int i = blockIdx.x * blockDim.x + threadIdx.x;
  if (i < n) deg[i] = 1;
}
__global__ void k_count(const int* __restrict__ ei, int* __restrict__ deg, int e) {
  int i = blockIdx.x * blockDim.x + threadIdx.x;
  if (i < e) atomicAdd(&deg[ei[e + i]], 1);
}
__global__ void k_dinv(const int* __restrict__ deg, float* __restrict__ dinv, int n) {
  int i = blockIdx.x * blockDim.x + threadIdx.x;
  if (i < n) dinv[i] = rsqrtf((float)deg[i]);
}
__global__ void k_scan(const int* __restrict__ deg, int* __restrict__ offs, int n) {
  __shared__ int sums[1024];
  int tid = threadIdx.x;
  int chunk = (n + 1023) / 1024;
  int s0 = tid * chunk, s1 = s0 + chunk;
  if (s1 > n) s1 = n;
  if (s0 > n) s0 = n;
  int s = 0;
  for (int i = s0; i < s1; i++) s += deg[i];
  sums[tid] = s;
  __syncthreads();
  if (tid == 0) {
    int acc = 0;
    for (int i = 0; i < 1024; i++) { int v = sums[i]; sums[i] = acc; acc += v; }
  }
  __syncthreads();
  int off = sums[tid];
  for (int i = s0; i < s1; i++) { offs[i] = off; off += deg[i]; }
  if (tid == 1023) offs[n] = off;
}
__global__ void k_copy_int(int* __restrict__ dst, const int* __restrict__ src, int n) {
  int i = blockIdx.x * blockDim.x + threadIdx.x;
  if (i < n) dst[i] = src[i];
}
__global__ void k_copy_u4(uint4* __restrict__ dst, const uint4* __restrict__ src, int n16) {
  int i = blockIdx.x * blockDim.x + threadIdx.x;
  int stride = gridDim.x * blockDim.x;
  for (; i < n16; i += stride) dst[i] = src[i];
}
__global__ void k_fill_edges(const int* __restrict__ ei, int e, int* __restrict__ cursor,
                             unsigned short* __restrict__ colv) {
  int i = blockIdx.x * blockDim.x + threadIdx.x;
  if (i < e) {
    int s = ei[i], d = ei[e + i];
    int pos = atomicAdd(&cursor[d], 1);
    colv[pos] = (unsigned short)s;
  }
}
__global__ void k_fill_loops(int* __restrict__ cursor, unsigned short* __restrict__ colv, int n) {
  int i = blockIdx.x * blockDim.x + threadIdx.x;
  if (i < n) {
    int pos = atomicAdd(&cursor[i], 1);
    colv[pos] = (unsigned short)i;
  }
}
// merged meta relocation (offs, colv, dinv -> ws copies) in one launch
__global__ void k_copy_meta(const int* __restrict__ offs, int* __restrict__ offs_c,
                            const int* __restrict__ colv, int* __restrict__ colv_c, int colv_ints,
                            const float* __restrict__ dinv, float* __restrict__ dinv_c, int n) {
  int i = blockIdx.x * blockDim.x + threadIdx.x;
  int stride = gridDim.x * blockDim.x;
  for (int k = i; k <= n; k += stride) offs_c[k] = offs[k];
  for (int k = i; k < colv_ints; k += stride) colv_c[k] = colv[k];
  for (int k = i; k < n; k += stride) dinv_c[k] = dinv[k];
}

// ---------------- conversions ----------------
__global__ void k_cvt_bf16(const float2* __restrict__ in, unsigned int* __restrict__ out, long long total) {
  long long i = (long long)blockIdx.x * blockDim.x + threadIdx.x;
  long long stride = (long long)gridDim.x * blockDim.x;
  for (; i < total; i += stride) {
    float2 v = in[i];
    out[i] = packb2(v.x, v.y);
  }
}
// in: [K][M] fp32 row-major -> out: [Mout][K] bf16 (rows >= M zero-filled)
__global__ void k_transpose_cvt(const float* __restrict__ in, unsigned short* __restrict__ out,
                                int K, int M, int Mout) {
  __shared__ float tile[32][33];
  int kb = blockIdx.x * 32;
  int mb = blockIdx.y * 32;
  int tx = threadIdx.x, ty = threadIdx.y;  // 32 x 8
#pragma unroll
  for (int j = 0; j < 4; j++) {
    int k = kb + ty + j * 8, m = mb + tx;
    tile[ty + j * 8][tx] = (k < K && m < M) ? in[(size_t)k * M + m] : 0.0f;
  }
  __syncthreads();
#pragma unroll
  for (int j = 0; j < 4; j++) {
    int m = mb + ty + j * 8, k = kb + tx;
    if (m < Mout && k < K) out[(size_t)m * K + k] = f2b(tile[tx][ty + j * 8]);
  }
}

// ---------------- layer-1 aggregation: bf16 gather (D=512) ----------------
__global__ void k_aggregate_512(const unsigned int* __restrict__ in, unsigned short* __restrict__ out,
                                const int* __restrict__ offs, const unsigned short* __restrict__ colv,
                                const float* __restrict__ dinv) {
  int i = blockIdx.x;
  int tid = threadIdx.x;  // 256 threads, 1 uint (2 bf16) each
  float di = dinv[i];
  int p0 = offs[i], p1 = offs[i + 1];
  float a0 = 0.f, a1 = 0.f;
  for (int p = p0; p < p1; p++) {
    int c = (int)colv[p];
    float wgt = dinv[c] * di;
    unsigned int u = in[(size_t)c * 256 + tid];
    a0 += wgt * blo(u); a1 += wgt * bhi(u);
  }
  ((unsigned int*)out)[(size_t)i * 256 + tid] = packb2(a0, a1);
}

// ---------------- layer-2 aggregation fused with pairnorm-apply + relu ----------------
__global__ void k_aggregate_pn(const unsigned short* __restrict__ in, unsigned short* __restrict__ outws,
                               unsigned short* __restrict__ outtail, int rsplit,
                               const int* __restrict__ offs, const unsigned short* __restrict__ colv,
                               const float* __restrict__ dinv, const float* __restrict__ meanv,
                               const float* __restrict__ scalev) {
  int i = blockIdx.x;
  int tid = threadIdx.x;
  float di = dinv[i];
  float s = scalev[0];
  float m[8];
#pragma unroll
  for (int j = 0; j < 8; j++) m[j] = meanv[tid * 8 + j];
  int p0 = offs[i], p1 = offs[i + 1];
  const uint4* inv = (const uint4*)in;
  float a[8] = {};
  for (int p = p0; p < p1; p++) {
    int c = (int)colv[p];
    float wgt = dinv[c] * di;
    uint4 u = inv[(size_t)c * 256 + tid];
    a[0] += wgt * fmaxf((blo(u.x) - m[0]) * s, 0.f);
    a[1] += wgt * fmaxf((bhi(u.x) - m[1]) * s, 0.f);
    a[2] += wgt * fmaxf((blo(u.y) - m[2]) * s, 0.f);
    a[3] += wgt * fmaxf((bhi(u.y) - m[3]) * s, 0.f);
    a[4] += wgt * fmaxf((blo(u.z) - m[4]) * s, 0.f);
    a[5] += wgt * fmaxf((bhi(u.z) - m[5]) * s, 0.f);
    a[6] += wgt * fmaxf((blo(u.w) - m[6]) * s, 0.f);
    a[7] += wgt * fmaxf((bhi(u.w) - m[7]) * s, 0.f);
  }
  uint4 o;
  o.x = packb2(a[0], a[1]); o.y = packb2(a[2], a[3]);
  o.z = packb2(a[4], a[5]); o.w = packb2(a[6], a[7]);
  char* base = (i < rsplit) ? (char*)outws + (size_t)i * 4096
                            : (char*)outtail + (size_t)(i - rsplit) * 4096;
  ((uint4*)base)[tid] = o;
}

// ================= 256x256 8-phase GEMM, deep prefetch (A: +2 tiles, B: +1 tile) =============
// r9 structure + nt C-stores (C not re-read soon; keep L2 for A panels, L3 for A full).
template <int MQ>
__device__ __forceinline__ void load_a(const char* ldsA, short8 (&a)[4][2], int wm, int lane) {
  const int frow = lane & 15;
  const int cb0 = (lane >> 4) << 4;
  const int xorb = (lane & 7) << 4;
#pragma unroll
  for (int i = 0; i < 4; i++)
#pragma unroll
    for (int kk = 0; kk < 2; kk++)
      a[i][kk] = *(const short8*)(ldsA + (wm * 128 + MQ * 64 + i * 16 + frow) * 128 +
                                  ((kk * 64 + cb0) ^ xorb));
}
template <int NQ>
__device__ __forceinline__ void load_b(const char* ldsB, short8 (&b)[2][2][2], int wn, int lane) {
  const int frow = lane & 15;
  const int cb0 = (lane >> 4) << 4;
  const int xorb = (lane & 7) << 4;
#pragma unroll
  for (int j = 0; j < 2; j++)
#pragma unroll
    for (int kk = 0; kk < 2; kk++)
      b[NQ][j][kk] = *(const short8*)(ldsB + (wn * 64 + NQ * 32 + j * 16 + frow) * 128 +
                                      ((kk * 64 + cb0) ^ xorb));
}
template <int MQ, int NQ>
__device__ __forceinline__ void mfma_q(short8 (&a)[4][2], short8 (&b)[2][2][2], f32x4 (&acc)[8][4]) {
  __builtin_amdgcn_s_setprio(1);
#pragma unroll
  for (int i = 0; i < 4; i++)
#pragma unroll
    for (int j = 0; j < 2; j++)
#pragma unroll
      for (int kk = 0; kk < 2; kk++)
        acc[MQ * 4 + i][NQ * 2 + j] =
            __builtin_amdgcn_mfma_f32_16x16x32_bf16(a[i][kk], b[NQ][j][kk], acc[MQ * 4 + i][NQ * 2 + j], 0, 0, 0);
  __builtin_amdgcn_s_setprio(0);
}

__global__ __launch_bounds__(512, 2) void k_gemm256(const unsigned short* __restrict__ A,
                                                    const char* __restrict__ a_tail, int rsplit,
                                                    const unsigned short* __restrict__ BT,
                                                    const float* __restrict__ bias,
                                                    float* __restrict__ colsum, float* __restrict__ ssq,
                                                    unsigned short* __restrict__ Cout,
                                                    int M, int K, int Nout, int m_base) {
  __shared__ __align__(16) char smem[131072];  // [Abuf0 32K][Bbuf0 32K][Abuf1 32K][Bbuf1 32K]
  const int t = threadIdx.x;
  const int lane = t & 63;
  const int wid = t >> 6;
  const int wm = wid >> 2, wn = wid & 3;
  int bx = blockIdx.x, by = blockIdx.y;
  xcd_remap(gridDim.x, gridDim.y, bx, by);
  const int n0 = bx * 256;
  const int m0 = m_base + by * 256;
  const size_t rowK = (size_t)K * 2;
  const int NT = K >> 6;

  const int rA = t >> 3;
  const int colS = (((t & 7) ^ ((t >> 3) & 7)) << 4);  // pre-swizzled source column (rule 21)

  auto rowptrA = [&](int r) -> const char* {
    int gr = m0 + r; if (gr >= M) gr = M - 1;
    return (gr < rsplit ? (const char*)A + (size_t)gr * rowK
                        : a_tail + (size_t)(gr - rsplit) * rowK) + colS;
  };
  const char* sA00 = rowptrA(rA);          // mq0,l0: LDS rows [0,64)
  const char* sA01 = rowptrA(128 + rA);    // mq0,l1: LDS rows [128,192)
  const char* sA10 = rowptrA(64 + rA);     // mq1,l0: LDS rows [64,128)
  const char* sA11 = rowptrA(192 + rA);    // mq1,l1: LDS rows [192,256)
  const int rbl = (t >> 8) * 64 + ((t >> 3) & 31);  // B row core
  const int rB00 = rbl, rB01 = 128 + rbl;           // nq0 l0/l1
  const int rB10 = 32 + rbl, rB11 = 160 + rbl;      // nq1 l0/l1
  const char* sB00 = (const char*)BT + (size_t)(n0 + rB00) * rowK + colS;
  const char* sB01 = (const char*)BT + (size_t)(n0 + rB01) * rowK + colS;
  const char* sB10 = (const char*)BT + (size_t)(n0 + rB10) * rowK + colS;
  const char* sB11 = (const char*)BT + (size_t)(n0 + rB11) * rowK + colS;
  const int t16 = t * 16;
  const int dA00 = t16, dA01 = 16384 + t16, dA10 = 8192 + t16, dA11 = 24576 + t16;
  const int c7 = (t & 7) * 16;
  const int dB00 = 32768 + rB00 * 128 + c7, dB01 = 32768 + rB01 * 128 + c7;
  const int dB10 = 32768 + rB10 * 128 + c7, dB11 = 32768 + rB11 * 128 + c7;

  f32x4 acc[8][4] = {};
  short8 a[4][2], b[2][2][2];

  // ---- prologue: tile0 -> buf0 (8 loads); A(t1) -> buf1 (4 loads); retire tile0 only ----
  gload_lds16(sA00, smem + dA00); gload_lds16(sA01, smem + dA01);
  gload_lds16(sA10, smem + dA10); gload_lds16(sA11, smem + dA11);
  gload_lds16(sB00, smem + dB00); gload_lds16(sB01, smem + dB01);
  gload_lds16(sB10, smem + dB10); gload_lds16(sB11, smem + dB11);
  gload_lds16(sA00 + 128, smem + 65536 + dA00); gload_lds16(sA01 + 128, smem + 65536 + dA01);
  gload_lds16(sA10 + 128, smem + 65536 + dA10); gload_lds16(sA11 + 128, smem + 65536 + dA11);
  sA00 += 256; sA01 += 256; sA10 += 256; sA11 += 256;  // A pointers now at tile kt+2 (kt=0)
  sB00 += 128; sB01 += 128; sB10 += 128; sB11 += 128;  // B pointers now at tile kt+1
  asm volatile("s_waitcnt vmcnt(4)" ::: "memory");     // tile0's 8 retired; A(t1) in flight
  asm volatile("s_barrier" ::: "memory");
  load_a<0>((const char*)smem, a, wm, lane);
  load_b<0>((const char*)smem + 32768, b, wn, lane);

  for (int kt = 0; kt < NT; ++kt) {
    const int cbo = (kt & 1) << 16;
    const int sbo = cbo ^ 65536;
    const char* LA = (const char*)smem + cbo;
    const char* LB = LA + 32768;
    const char* NA = (const char*)smem + sbo;
    const char* NB = NA + 32768;
    char* SB = smem + sbo;   // B dest: tile kt+1
    char* SA = smem + cbo;   // A dest: tile kt+2 (current A region consumed by ph1-end)
    // ---- ph0 (mq0,nq0): stage B0(kt+1) | vmcnt(6) | MFMA | preload b1<-B1(kt) ----
    gload_lds16(sB00, SB + dB00); gload_lds16(sB01, SB + dB01);
    asm volatile("s_waitcnt vmcnt(6)" ::: "memory");
    asm volatile("s_barrier" ::: "memory");
    mfma_q<0, 0>(a, b, acc);
    load_b<1>(LB, b, wn, lane);
    __builtin_amdgcn_sched_barrier(0);
    asm volatile("s_barrier" ::: "memory");
    // ---- ph1 (mq0,nq1): stage B1(kt+1) | MFMA | preload a<-A1(kt) ----
    gload_lds16(sB10, SB + dB10); gload_lds16(sB11, SB + dB11);
    asm volatile("s_barrier" ::: "memory");
    mfma_q<0, 1>(a, b, acc);
    load_a<1>(LA, a, wm, lane);
    __builtin_amdgcn_sched_barrier(0);
    asm volatile("s_barrier" ::: "memory");
    // ---- ph2 (mq1,nq0): stage A0(kt+2) into CURRENT buffer | MFMA ----
    gload_lds16(sA00, SA + dA00); gload_lds16(sA01, SA + dA01);
    asm volatile("s_barrier" ::: "memory");
    mfma_q<1, 0>(a, b, acc);
    __builtin_amdgcn_sched_barrier(0);
    asm volatile("s_barrier" ::: "memory");
    // ---- ph3 (mq1,nq1): stage A1(kt+2) | vmcnt(6) | MFMA | preload a,b0 of tile kt+1 ----
    gload_lds16(sA10, SA + dA10); gload_lds16(sA11, SA + dA11);
    asm volatile("s_waitcnt vmcnt(6)" ::: "memory");
    asm volatile("s_barrier" ::: "memory");
    mfma_q<1, 1>(a, b, acc);
    load_a<0>(NA, a, wm, lane);
    load_b<0>(NB, b, wn, lane);
    __builtin_amdgcn_sched_barrier(0);
    asm volatile("s_barrier" ::: "memory");
    sA00 += 128; sA01 += 128; sA10 += 128; sA11 += 128;
    sB00 += 128; sB01 += 128; sB10 += 128; sB11 += 128;
  }
  // tail lookahead reads at most 256B past each row's K extent -> lands in adjacent
  // allocated regions, data never consumed as valid.

  // ---- epilogue: bias + nt bf16 store + fused column stats ----
  const int rrow = (lane >> 4) * 4;
  const int ccol = lane & 15;
  float ss = 0.f;
  float csum[4] = {0.f, 0.f, 0.f, 0.f};
#pragma unroll
  for (int f = 0; f < 8; f++) {
#pragma unroll
    for (int g = 0; g < 4; g++) {
      int col = n0 + wn * 64 + g * 16 + ccol;
      float bv = bias[col];
#pragma unroll
      for (int r = 0; r < 4; r++) {
        int row = m0 + wm * 128 + f * 16 + rrow + r;
        if (row < M) {
          float v = acc[f][g][r] + bv;
          __builtin_nontemporal_store(f2b(v), &Cout[(size_t)row * Nout + col]);
          csum[g] += v; ss += v * v;
        }
      }
    }
  }
#pragma unroll
  for (int g = 0; g < 4; g++) {
    float w = csum[g];
    w += __shfl_xor(w, 16);
    w += __shfl_xor(w, 32);
    if (lane < 16) atomicAdd(&colsum[n0 + wn * 64 + g * 16 + lane], w);
  }
  for (int mk = 32; mk >= 1; mk >>= 1) ss += __shfl_xor(ss, mk);
  if (lane == 0) atomicAdd(ssq, ss);
}

// ---------------- layer-3 GEMM with fused pairnorm+relu on A ----------------
__global__ __launch_bounds__(256) void k_gemm3_pn(const unsigned short* __restrict__ A,
                                                  const float* __restrict__ meanv,
                                                  const float* __restrict__ scalev,
                                                  const unsigned short* __restrict__ BT,
                                                  float* __restrict__ Cout,
                                                  int M, int K, int Nout) {
  constexpr int BK = 64;
  constexpr int FN = 4;
  __shared__ __align__(16) unsigned short lA[64 * BK];
  __shared__ __align__(16) unsigned short lB[64 * BK];
  const int tid = threadIdx.x;
  const int lane = tid & 63;
  const int wid = tid >> 6;
  const int m0 = blockIdx.y * 64;
  const int wrow = wid * 16;
  const size_t rowK = (size_t)K * 2;
  const float s = scalev[0];

  f32x4 acc[FN] = {};
  const int frow = lane & 15;
  const int kcol8 = (lane >> 4) * 8;
  const int xorb = (lane & 7) << 4;

  for (int k0 = 0; k0 < K; k0 += BK) {
#pragma unroll
    for (int c = 0; c < 2; c++) {
      int o = c * 4096 + tid * 16;
      int r = o >> 7;
      int kb = o & 127;
      int gr = m0 + r; if (gr >= M) gr = M - 1;
      uint4 u = *(const uint4*)((const char*)A + (size_t)gr * rowK + (size_t)k0 * 2 + kb);
      int col = k0 + (kb >> 1);
      float4 m0v = *(const float4*)&meanv[col];
      float4 m1v = *(const float4*)&meanv[col + 4];
      uint4 g;
      g.x = packb2(fmaxf((blo(u.x) - m0v.x) * s, 0.f), fmaxf((bhi(u.x) - m0v.y) * s, 0.f));
      g.y = packb2(fmaxf((blo(u.y) - m0v.z) * s, 0.f), fmaxf((bhi(u.y) - m0v.w) * s, 0.f));
      g.z = packb2(fmaxf((blo(u.z) - m1v.x) * s, 0.f), fmaxf((bhi(u.z) - m1v.y) * s, 0.f));
      g.w = packb2(fmaxf((blo(u.w) - m1v.z) * s, 0.f), fmaxf((bhi(u.w) - m1v.w) * s, 0.f));
      *(uint4*)((char*)lA + (o ^ ((r & 7) << 4))) = g;
    }
#pragma unroll
    for (int c = 0; c < 2; c++) {
      int o = c * 4096 + tid * 16;
      int r = o >> 7;
      int kbs = (o & 127) ^ ((r & 7) << 4);
      gload_lds16((const char*)BT + (size_t)r * rowK + (size_t)k0 * 2 + kbs, (char*)lB + o);
    }
    __syncthreads();
#pragma unroll
    for (int kk = 0; kk < BK; kk += 32) {
      short8 af = *(const short8*)((const char*)lA + (wrow + frow) * 128 + (((kk + kcol8) * 2) ^ xorb));
#pragma unroll
      for (int u = 0; u < FN; u++) {
        short8 bf = *(const short8*)((const char*)lB + (u * 16 + frow) * 128 + (((kk + kcol8) * 2) ^ xorb));
        acc[u] = __builtin_amdgcn_mfma_f32_16x16x32_bf16(af, bf, acc[u], 0, 0, 0);
      }
    }
    __syncthreads();
  }

  const int rrow = (lane >> 4) * 4;
  const int ccol = lane & 15;
#pragma unroll
  for (int u = 0; u < FN; u++) {
#pragma unroll
    for (int r = 0; r < 4; r++) {
      int row = m0 + wrow + rrow + r;
      int col = u * 16 + ccol;
      if (row < M && col < Nout)
        Cout[(size_t)row * Nout + col] = acc[u][r];
    }
  }
}

// ---------------- pairnorm scalars ----------------
__global__ void k_zero_stats(float* colsum, float* ssq, int n) {
  int i = blockIdx.x * blockDim.x + threadIdx.x;
  if (i < n) colsum[i] = 0.f;
  if (i == 0) ssq[0] = 0.f;
}
// computes meanv/scalev, then re-zeroes colsum/ssq for the next layer's atomics
__global__ void k_finalize(float* __restrict__ colsum, float* __restrict__ ssq,
                           float* __restrict__ meanv, float* __restrict__ scalev, int nrows, int ncols) {
  __shared__ float red[1024];
  int tid = threadIdx.x;
  float m2 = 0.f;
  for (int c = tid; c < ncols; c += 1024) {
    float m = colsum[c] / (float)nrows;
    meanv[c] = m;
    m2 += m * m;
    colsum[c] = 0.f;
  }
  red[tid] = m2;
  __syncthreads();
  for (int s = 512; s > 0; s >>= 1) {
    if (tid < s) red[tid] += red[tid + s];
    __syncthreads();
  }
  if (tid == 0) {
    float sstot = ssq[0] - (float)nrows * red[0];
    scalev[0] = rsqrtf(1e-6f + sstot / (float)nrows);
    ssq[0] = 0.f;
  }
}

// ---------------- final aggregation at D=40 (fp32) + bias, 4 rows/block ----------------
__global__ void k_aggregate_out(const float* __restrict__ t, const int* __restrict__ offs,
                                const unsigned short* __restrict__ colv, const float* __restrict__ dinv,
                                const float* __restrict__ b3, float* __restrict__ outp, int n, int ncls) {
  int i = blockIdx.x * 4 + (threadIdx.x >> 6);
  int j = threadIdx.x & 63;
  if (i < n && j < ncls) {
    float di = dinv[i];
    float acc = b3[j];
    for (int p = offs[i]; p < offs[i + 1]; p++) {
      int c = (int)colv[p];
      acc += dinv[c] * di * t[(size_t)c * ncls + j];
    }
    outp[(size_t)i * ncls + j] = acc;
  }
}

extern "C" void kernel_launch(void* const* d_in, const int* in_sizes, int n_in,
                              void* d_out, int out_size, void* d_ws, size_t ws_size,
                              hipStream_t stream) {
  (void)n_in;
  const float* x = (const float*)d_in[0];
  const int* ei = (const int*)d_in[1];
  const float* W1 = (const float*)d_in[2];
  const float* b1 = (const float*)d_in[3];
  const float* W2 = (const float*)d_in[4];
  const float* b2 = (const float*)d_in[5];
  const float* W3 = (const float*)d_in[6];
  const float* b3 = (const float*)d_in[7];
  const int DI = 512, DH = 2048, NC = 40;
  const int n = in_sizes[0] / DI;  // 50000
  const int e = in_sizes[1] / 2;   // 200000

  // ---- memory plan (ws ~390MB + d_out 8MB overlay) ----
  const size_t BIG1B = (size_t)n * DH * 2;  // 204,800,000
  char* BIG1 = (char*)d_ws;
  char* BIG2 = (char*)d_ws + BIG1B;

  char* dob = (char*)d_out;
  int* deg = (int*)(dob + 0);
  float* dinv = (float*)(dob + 200064);
  int* offs = (int*)(dob + 400128);
  unsigned short* colv = (unsigned short*)(dob + 600192);
  float* colsum = (float*)(dob + 1100288);
  float* meanv = (float*)(dob + 1108480);
  float* ssq = (float*)(dob + 1116672);
  float* scalev = (float*)(dob + 1116928);
  char* aggtail = dob + 2097152;

  long long rows_ws = (long long)(ws_size - BIG1B) / (DH * 2);
  int rsplit = (rows_ws > n) ? n : (int)rows_ws;

  if (ws_size < 403800000UL || rsplit < 48560) {
    float v = (float)(double)(ws_size >> 20);
    k_sentinel<<<512, 256, 0, stream>>>((float*)d_out, (long long)out_size, v);
    return;
  }

  const int W2ROW0 = 47952;
  unsigned short* WT2 = (unsigned short*)(BIG1 + (size_t)W2ROW0 * 4096);
  const int PH2_MBASE = 47872;                          // 187 * 256
  const int PH2_TILES = (n - PH2_MBASE + 255) / 256;    // 9

  unsigned short* agg1 = (unsigned short*)BIG2;                 // n x 512 bf16
  unsigned short* xb = (unsigned short*)(BIG2 + 64000000);      // n x 512 bf16 (x in bf16)
  unsigned short* WT1 = (unsigned short*)(BIG2 + 120000000);    // 2 MiB
  unsigned short* agg2 = (unsigned short*)BIG2;                 // n x 2048 bf16 (rows < rsplit)
  unsigned short* WT2c = (unsigned short*)BIG2;                 // WT2 copy (rows 0..2047 dead after ph1)
  float* tbuf = (float*)BIG2;                                   // n x 40 f32
  unsigned short* WT3 = (unsigned short*)(BIG2 + 9000000);
  int* offs_c = (int*)(BIG2 + 10000000);
  unsigned short* colv_c = (unsigned short*)(BIG2 + 11000000);
  float* dinv_c = (float*)(BIG2 + 12000000);

  dim3 b256(256);
  dim3 b512(512);
  int gn = (n + 255) / 256, ge = (e + 255) / 256;

  // ---- graph prep ----
  k_init_deg<<<gn, b256, 0, stream>>>(deg, n);
  k_count<<<ge, b256, 0, stream>>>(ei, deg, e);
  k_dinv<<<gn, b256, 0, stream>>>(deg, dinv, n);
  k_scan<<<1, 1024, 0, stream>>>(deg, offs, n);
  k_copy_int<<<gn, b256, 0, stream>>>(deg, offs, n);
  k_fill_edges<<<ge, b256, 0, stream>>>(ei, e, deg, colv);
  k_fill_loops<<<gn, b256, 0, stream>>>(deg, colv, n);

  dim3 tb(32, 8);

  // ---- layer 1: h1 = (A @ x) @ W1 + b1 (stats fused) ----
  k_cvt_bf16<<<2048, b256, 0, stream>>>((const float2*)x, (unsigned int*)xb, (long long)n * DI / 2);
  k_aggregate_512<<<n, b256, 0, stream>>>((const unsigned int*)xb, agg1, offs, colv, dinv);
  k_transpose_cvt<<<dim3(DI / 32, DH / 32), tb, 0, stream>>>(W1, WT1, DI, DH, DH);
  k_zero_stats<<<(DH + 255) / 256, b256, 0, stream>>>(colsum, ssq, DH);
  k_gemm256<<<dim3(DH / 256, (n + 255) / 256), b512, 0, stream>>>(
      agg1, (const char*)agg1, n, WT1, b1, colsum, ssq, (unsigned short*)BIG1, n, DI, DH, 0);
  k_finalize<<<1, 1024, 0, stream>>>(colsum, ssq, meanv, scalev, n, DH);  // also re-zeroes stats

  // ---- layer 2: h2 = (A @ relu(pn(h1))) @ W2 + b2 ----
  k_aggregate_pn<<<n, b256, 0, stream>>>((const unsigned short*)BIG1, agg2, (unsigned short*)aggtail,
                                         rsplit, offs, colv, dinv, meanv, scalev);
  k_transpose_cvt<<<dim3(DH / 32, DH / 32), tb, 0, stream>>>(W2, WT2, DH, DH, DH);
  // phase 1: rows [0, 47872) — does not write the WT2 region (>= 47952)
  k_gemm256<<<dim3(DH / 256, 187), b512, 0, stream>>>(
      agg2, aggtail, rsplit, WT2, b2, colsum, ssq, (unsigned short*)BIG1, n, DH, DH, 0);
  // agg2 rows 0..2047 dead -> copy WT2 there, then finish rows [47872, n)
  k_copy_u4<<<2048, b256, 0, stream>>>((uint4*)WT2c, (const uint4*)WT2, (int)(8388608 / 16));
  k_gemm256<<<dim3(DH / 256, PH2_TILES), b512, 0, stream>>>(
      agg2, aggtail, rsplit, WT2c, b2, colsum, ssq, (unsigned short*)BIG1, n, DH, DH, PH2_MBASE);
  k_finalize<<<1, 1024, 0, stream>>>(colsum, ssq, meanv, scalev, n, DH);

  // ---- layer 3: out = A @ (relu(pn(h2)) @ W3) + b3  (pn fused into GEMM3 A-staging) ----
  k_transpose_cvt<<<dim3(DH / 32, 2), tb, 0, stream>>>(W3, WT3, DH, NC, 64);
  k_gemm3_pn<<<dim3(1, (n + 63) / 64), b256, 0, stream>>>(
      (const unsigned short*)BIG1, meanv, scalev, WT3, tbuf, n, DH, NC);
  k_copy_meta<<<256, b256, 0, stream>>>(offs, offs_c, (const int*)colv, (int*)colv_c, (e + n) / 2,
                                        dinv, dinv_c, n);
  k_aggregate_out<<<(n + 3) / 4, b256, 0, stream>>>(tbuf, offs_c, colv_c, dinv_c, b3,
                                                    (float*)d_out, n, NC);
}